// Round 1
// baseline (2771.891 us; speedup 1.0000x reference)
//
#include <hip/hip_runtime.h>

namespace {

constexpr int Cc   = 128;   // channels
constexpr int Tt   = 49;    // tokens per 7x7 window
constexpr int Wimg = 112;   // H = W = 112

__global__ __launch_bounds__(256, 1)
void swin_fused(const float* __restrict__ x,
                const float* __restrict__ lng,
                const float* __restrict__ lnb,
                const float* __restrict__ wqkv,
                const float* __restrict__ bqkv,
                const float* __restrict__ wmo,
                const float* __restrict__ bmo,
                const float* __restrict__ wout,
                const float* __restrict__ bout,
                float* __restrict__ out)
{
    __shared__ float sN[Tt][132];   // LN output, later attention output (cols 0..127; +4 pad vs bank conflicts)
    __shared__ float sQ[Tt][388];   // QKV (q|k|v), later MO output in cols 0..127 (+4 pad)

    const int wid  = blockIdx.x;          // 0..4095
    const int b    = wid >> 8;            // image
    const int wh   = (wid >> 4) & 15;     // window row
    const int ww   = wid & 15;            // window col
    const int t    = threadIdx.x;
    const int lane = t & 63;
    const int wv   = t >> 6;              // wave 0..3

    const size_t base = ((size_t)(b * Wimg + wh * 7) * Wimg + ww * 7) * Cc;
    // token r (0..48) lives at global offset: base + ((r/7)*112 + (r%7))*128

    // ---------------- LayerNorm (one wave per row, 2 ch/lane) ----------------
    {
        const int c0 = lane * 2;
        const float g0 = lng[c0], g1 = lng[c0 + 1];
        const float b0 = lnb[c0], b1 = lnb[c0 + 1];
        for (int r = wv; r < Tt; r += 4) {
            const float* xr = x + base + (size_t)((r / 7) * Wimg + (r % 7)) * Cc;
            float2 v = *reinterpret_cast<const float2*>(xr + c0);
            float s1 = v.x + v.y;
            float s2 = v.x * v.x + v.y * v.y;
            #pragma unroll
            for (int m = 1; m < 64; m <<= 1) {
                s1 += __shfl_xor(s1, m);
                s2 += __shfl_xor(s2, m);
            }
            const float mu  = s1 * (1.0f / 128.0f);
            const float var = s2 * (1.0f / 128.0f) - mu * mu;
            const float inv = rsqrtf(var + 1e-5f);
            sN[r][c0]     = (v.x - mu) * inv * g0 + b0;
            sN[r][c0 + 1] = (v.y - mu) * inv * g1 + b1;
        }
    }
    __syncthreads();

    const int c = t & 127;     // output column within q/k/v
    const int g = t >> 7;      // row group: 0 -> rows 0..24, 1 -> rows 25..48

    // ---------------- QKV projection: sQ[r][o] = sum_i sN[r][i]*w_qkv[o][i] + b ----------------
    {
        float aq[25], ak[25], av[25];
        const float bq = bqkv[c], bk = bqkv[Cc + c], bv = bqkv[2 * Cc + c];
        #pragma unroll
        for (int k = 0; k < 25; ++k) { aq[k] = bq; ak[k] = bk; av[k] = bv; }
        const float4* wq4 = reinterpret_cast<const float4*>(wqkv + (size_t)c * Cc);
        const float4* wk4 = reinterpret_cast<const float4*>(wqkv + (size_t)(Cc + c) * Cc);
        const float4* wv4 = reinterpret_cast<const float4*>(wqkv + (size_t)(2 * Cc + c) * Cc);
        for (int i4 = 0; i4 < 32; ++i4) {
            const float4 wq = wq4[i4];
            const float4 wk = wk4[i4];
            const float4 wvv = wv4[i4];
            #pragma unroll
            for (int k = 0; k < 25; ++k) {
                const int r = g * 25 + k;
                if (r < Tt) {
                    const float4 nv = *reinterpret_cast<const float4*>(&sN[r][i4 * 4]);
                    aq[k] += nv.x * wq.x + nv.y * wq.y + nv.z * wq.z + nv.w * wq.w;
                    ak[k] += nv.x * wk.x + nv.y * wk.y + nv.z * wk.z + nv.w * wk.w;
                    av[k] += nv.x * wvv.x + nv.y * wvv.y + nv.z * wvv.z + nv.w * wvv.w;
                }
            }
        }
        #pragma unroll
        for (int k = 0; k < 25; ++k) {
            const int r = g * 25 + k;
            if (r < Tt) {
                sQ[r][c]          = aq[k];
                sQ[r][Cc + c]     = ak[k];
                sQ[r][2 * Cc + c] = av[k];
            }
        }
    }
    __syncthreads();

    // ---------------- attention: wave wv <-> head wv, lane <-> query row ----------------
    {
        const int h  = wv;
        const int hb = h * 32;
        const int i  = (lane < Tt) ? lane : (Tt - 1);   // clamp idle lanes into range
        float q[32];
        #pragma unroll
        for (int d4 = 0; d4 < 8; ++d4) {
            const float4 v = *reinterpret_cast<const float4*>(&sQ[i][hb + d4 * 4]);
            q[d4 * 4 + 0] = v.x; q[d4 * 4 + 1] = v.y;
            q[d4 * 4 + 2] = v.z; q[d4 * 4 + 3] = v.w;
        }
        float s[Tt];
        #pragma unroll
        for (int j = 0; j < Tt; ++j) {
            float acc = 0.0f;
            #pragma unroll
            for (int d4 = 0; d4 < 8; ++d4) {
                const float4 kv = *reinterpret_cast<const float4*>(&sQ[j][Cc + hb + d4 * 4]);
                acc += q[d4 * 4 + 0] * kv.x + q[d4 * 4 + 1] * kv.y
                     + q[d4 * 4 + 2] * kv.z + q[d4 * 4 + 3] * kv.w;
            }
            s[j] = acc * 0.17677669529663687f;   // 1/sqrt(32)
        }
        float mx = s[0];
        #pragma unroll
        for (int j = 1; j < Tt; ++j) mx = fmaxf(mx, s[j]);
        float sum = 0.0f;
        #pragma unroll
        for (int j = 0; j < Tt; ++j) { s[j] = __expf(s[j] - mx); sum += s[j]; }
        const float rs = 1.0f / sum;
        float o[32];
        #pragma unroll
        for (int d = 0; d < 32; ++d) o[d] = 0.0f;
        #pragma unroll
        for (int j = 0; j < Tt; ++j) {
            const float p = s[j] * rs;
            #pragma unroll
            for (int d4 = 0; d4 < 8; ++d4) {
                const float4 vv = *reinterpret_cast<const float4*>(&sQ[j][2 * Cc + hb + d4 * 4]);
                o[d4 * 4 + 0] += p * vv.x; o[d4 * 4 + 1] += p * vv.y;
                o[d4 * 4 + 2] += p * vv.z; o[d4 * 4 + 3] += p * vv.w;
            }
        }
        if (lane < Tt) {
            #pragma unroll
            for (int d4 = 0; d4 < 8; ++d4) {
                float4 v;
                v.x = o[d4 * 4 + 0]; v.y = o[d4 * 4 + 1];
                v.z = o[d4 * 4 + 2]; v.w = o[d4 * 4 + 3];
                *reinterpret_cast<float4*>(&sN[i][hb + d4 * 4]) = v;
            }
        }
    }
    __syncthreads();

    // ---------------- MO projection: sQ[r][c] = attn_out @ w_mo^T + b_mo ----------------
    {
        float am[25];
        const float bm = bmo[c];
        #pragma unroll
        for (int k = 0; k < 25; ++k) am[k] = bm;
        const float4* wm4 = reinterpret_cast<const float4*>(wmo + (size_t)c * Cc);
        for (int i4 = 0; i4 < 32; ++i4) {
            const float4 w = wm4[i4];
            #pragma unroll
            for (int k = 0; k < 25; ++k) {
                const int r = g * 25 + k;
                if (r < Tt) {
                    const float4 nv = *reinterpret_cast<const float4*>(&sN[r][i4 * 4]);
                    am[k] += nv.x * w.x + nv.y * w.y + nv.z * w.z + nv.w * w.w;
                }
            }
        }
        #pragma unroll
        for (int k = 0; k < 25; ++k) {
            const int r = g * 25 + k;
            if (r < Tt) sQ[r][c] = am[k];
        }
    }
    __syncthreads();

    // ---------------- OUT projection + residual: out = x + mo @ w_out^T + b_out ----------------
    {
        float ao[25];
        const float bo = bout[c];
        #pragma unroll
        for (int k = 0; k < 25; ++k) ao[k] = bo;
        const float4* wo4 = reinterpret_cast<const float4*>(wout + (size_t)c * Cc);
        for (int i4 = 0; i4 < 32; ++i4) {
            const float4 w = wo4[i4];
            #pragma unroll
            for (int k = 0; k < 25; ++k) {
                const int r = g * 25 + k;
                if (r < Tt) {
                    const float4 nv = *reinterpret_cast<const float4*>(&sQ[r][i4 * 4]);
                    ao[k] += nv.x * w.x + nv.y * w.y + nv.z * w.z + nv.w * w.w;
                }
            }
        }
        #pragma unroll
        for (int k = 0; k < 25; ++k) {
            const int r = g * 25 + k;
            if (r < Tt) {
                const size_t gi = base + (size_t)((r / 7) * Wimg + (r % 7)) * Cc + c;
                out[gi] = x[gi] + ao[k];
            }
        }
    }
}

} // namespace

extern "C" void kernel_launch(void* const* d_in, const int* in_sizes, int n_in,
                              void* d_out, int out_size, void* d_ws, size_t ws_size,
                              hipStream_t stream) {
    const float* x    = (const float*)d_in[0];
    const float* lng  = (const float*)d_in[1];
    const float* lnb  = (const float*)d_in[2];
    const float* wqkv = (const float*)d_in[3];
    const float* bqkv = (const float*)d_in[4];
    const float* wmo  = (const float*)d_in[5];
    const float* bmo  = (const float*)d_in[6];
    const float* wout = (const float*)d_in[7];
    const float* bout = (const float*)d_in[8];
    float* out = (float*)d_out;

    // 16 images x 16x16 windows = 4096 workgroups, 256 threads (4 waves) each
    swin_fused<<<4096, 256, 0, stream>>>(x, lng, lnb, wqkv, bqkv, wmo, bmo,
                                         wout, bout, out);
}

// Round 2
// 186.621 us; speedup vs baseline: 14.8531x; 14.8531x over previous
//
#include <hip/hip_runtime.h>

namespace {

typedef __attribute__((ext_vector_type(8))) short bf16x8;
typedef __attribute__((ext_vector_type(4))) float f32x4;

__device__ __forceinline__ unsigned f2b_u(float f) {
    union { float f; unsigned u; } v; v.f = f;
    unsigned r = v.u + 0x7fffu + ((v.u >> 16) & 1u);   // round-to-nearest-even
    return r >> 16;
}

__device__ __forceinline__ int SWZ(int byteoff, int row) {
    return byteoff ^ ((row & 7) << 4);
}

// LDS layout (bytes). Row-major bf16 tiles: 64 rows x 256B (128 bf16), XOR-swizzled.
constexpr int SX  = 0;        // LN out [64][128]bf16; later attn-out (sAo). rows 49..63 zero
constexpr int SQo = 16384;    // Q [64][128]; later sP (4 heads x [64][64]bf16 = 8192B each spanning SQo..SQo+32768); later sMo
constexpr int SKo = 32768;    // K [64][128]
constexpr int SVt = 49152;    // V transposed [128 d][64 j]bf16, 128B rows, swizzled by (d&7)
constexpr int SRS = 65536;    // 1/rowsum  [4 heads][64 i] f32
constexpr int LDS_BYTES = 66560;

template<bool USEWS>
__device__ __forceinline__ bf16x8 load_wfrag(const unsigned short* wsb, const float* wf, int idx) {
    if constexpr (USEWS) {
        return *(const bf16x8*)(wsb + idx);
    } else {
        const float4 f0 = *(const float4*)(wf + idx);
        const float4 f1 = *(const float4*)(wf + idx + 4);
        bf16x8 r;
        r[0] = (short)f2b_u(f0.x); r[1] = (short)f2b_u(f0.y);
        r[2] = (short)f2b_u(f0.z); r[3] = (short)f2b_u(f0.w);
        r[4] = (short)f2b_u(f1.x); r[5] = (short)f2b_u(f1.y);
        r[6] = (short)f2b_u(f1.z); r[7] = (short)f2b_u(f1.w);
        return r;
    }
}

__global__ void conv_w(const float* __restrict__ wqkv, const float* __restrict__ wmo,
                       const float* __restrict__ wout, unsigned short* __restrict__ dst) {
    int i = blockIdx.x * 256 + threadIdx.x;
    float v;
    if (i < 49152)       v = wqkv[i];
    else if (i < 65536)  v = wmo[i - 49152];
    else if (i < 81920)  v = wout[i - 65536];
    else return;
    dst[i] = (unsigned short)f2b_u(v);
}

template<bool USEWS>
__global__ __launch_bounds__(256, 2)
void swin_mfma(const float* __restrict__ x,
               const float* __restrict__ lng, const float* __restrict__ lnb,
               const float* __restrict__ wqkv, const float* __restrict__ bqkv,
               const float* __restrict__ wmo,  const float* __restrict__ bmo,
               const float* __restrict__ wout, const float* __restrict__ bout,
               const unsigned short* __restrict__ wsb,   // bf16 weights: qkv@0, mo@49152, out@65536
               float* __restrict__ out)
{
    __shared__ char lds[LDS_BYTES];

    const int wid  = blockIdx.x;
    const int b    = wid >> 8;
    const int wh   = (wid >> 4) & 15;
    const int ww   = wid & 15;
    const int t    = threadIdx.x;
    const int lane = t & 63;
    const int wv   = t >> 6;          // wave 0..3
    const int lr   = lane & 15;       // fragment row/col lane index
    const int g    = lane >> 4;       // fragment k-group 0..3

    const size_t base = ((size_t)(b * 112 + wh * 7) * 112 + ww * 7) * 128;

    // ---------- phase 0: zero sX pad rows 49..63, LayerNorm -> sX (bf16, swizzled) ----------
    if (t < 240) *(f32x4*)(lds + SX + 49 * 256 + t * 16) = f32x4{0.f, 0.f, 0.f, 0.f};
    {
        const int c0 = lane * 2;
        const float g0 = lng[c0], g1 = lng[c0 + 1];
        const float be0 = lnb[c0], be1 = lnb[c0 + 1];
        for (int r = wv; r < 49; r += 4) {
            const float* xr = x + base + (size_t)((r / 7) * 112 + (r % 7)) * 128;
            float2 v = *(const float2*)(xr + c0);
            float s1 = v.x + v.y;
            float s2 = v.x * v.x + v.y * v.y;
            #pragma unroll
            for (int m = 1; m < 64; m <<= 1) {
                s1 += __shfl_xor(s1, m);
                s2 += __shfl_xor(s2, m);
            }
            const float mu  = s1 * (1.0f / 128.0f);
            const float var = s2 * (1.0f / 128.0f) - mu * mu;
            const float inv = rsqrtf(var + 1e-5f);
            const float y0 = (v.x - mu) * inv * g0 + be0;
            const float y1 = (v.y - mu) * inv * g1 + be1;
            unsigned p = f2b_u(y0) | (f2b_u(y1) << 16);
            *(unsigned*)(lds + SX + r * 256 + SWZ(4 * lane, r)) = p;
        }
    }
    __syncthreads();

    // ---------- phase 1: QKV projection (MFMA). wave wv -> out cols [96*wv, 96*wv+96) ----------
    {
        bf16x8 a[4][4];
        #pragma unroll
        for (int mt = 0; mt < 4; ++mt)
            #pragma unroll
            for (int kk = 0; kk < 4; ++kk) {
                int row = mt * 16 + lr;
                a[mt][kk] = *(bf16x8*)(lds + SX + row * 256 + SWZ(g * 16 + kk * 64, row));
            }
        #pragma unroll
        for (int nt = 0; nt < 6; ++nt) {
            const int ob = wv * 96 + nt * 16 + lr;   // global out col 0..383 (uniform segment per tile)
            bf16x8 bfr[4];
            #pragma unroll
            for (int kk = 0; kk < 4; ++kk)
                bfr[kk] = load_wfrag<USEWS>(wsb, wqkv, ob * 128 + g * 8 + kk * 32);
            f32x4 acc[4];
            #pragma unroll
            for (int mt = 0; mt < 4; ++mt) acc[mt] = f32x4{0.f, 0.f, 0.f, 0.f};
            #pragma unroll
            for (int kk = 0; kk < 4; ++kk)
                #pragma unroll
                for (int mt = 0; mt < 4; ++mt)
                    acc[mt] = __builtin_amdgcn_mfma_f32_16x16x32_bf16(a[mt][kk], bfr[kk], acc[mt], 0, 0, 0);
            const float bias = bqkv[ob];
            const int seg = wv * 96 + nt * 16;   // wave-uniform tile base
            if (seg < 128) {            // Q (pre-scaled by 1/sqrt(hd))
                #pragma unroll
                for (int mt = 0; mt < 4; ++mt)
                    #pragma unroll
                    for (int r = 0; r < 4; ++r) {
                        int row = mt * 16 + g * 4 + r;
                        float v = (acc[mt][r] + bias) * 0.17677669529663687f;
                        *(short*)(lds + SQo + row * 256 + SWZ(ob * 2, row)) = (short)f2b_u(v);
                    }
            } else if (seg < 256) {     // K
                const int c = ob - 128;
                #pragma unroll
                for (int mt = 0; mt < 4; ++mt)
                    #pragma unroll
                    for (int r = 0; r < 4; ++r) {
                        int row = mt * 16 + g * 4 + r;
                        *(short*)(lds + SKo + row * 256 + SWZ(c * 2, row)) = (short)f2b_u(acc[mt][r] + bias);
                    }
            } else {                    // V, stored transposed sVt[d][j]
                const int d = ob - 256;
                #pragma unroll
                for (int mt = 0; mt < 4; ++mt) {
                    int j0 = mt * 16 + g * 4;
                    unsigned lo = f2b_u(acc[mt][0] + bias) | (f2b_u(acc[mt][1] + bias) << 16);
                    unsigned hi = f2b_u(acc[mt][2] + bias) | (f2b_u(acc[mt][3] + bias) << 16);
                    *(uint2*)(lds + SVt + d * 128 + SWZ(j0 * 2, d)) = uint2{lo, hi};
                }
            }
        }
    }
    __syncthreads();

    // ---------- phase 2: scores = mfma(K, Q) per head; in-register softmax ----------
    const int h  = wv;
    const int hb = h * 32;
    f32x4 sc[4][4];
    {
        bf16x8 ak[4], bq[4];
        #pragma unroll
        for (int mtj = 0; mtj < 4; ++mtj) {
            int row = mtj * 16 + lr;
            ak[mtj] = *(bf16x8*)(lds + SKo + row * 256 + SWZ(hb * 2 + g * 16, row));
        }
        #pragma unroll
        for (int nti = 0; nti < 4; ++nti) {
            int row = nti * 16 + lr;
            bq[nti] = *(bf16x8*)(lds + SQo + row * 256 + SWZ(hb * 2 + g * 16, row));
        }
        #pragma unroll
        for (int mtj = 0; mtj < 4; ++mtj)
            #pragma unroll
            for (int nti = 0; nti < 4; ++nti)
                sc[mtj][nti] = __builtin_amdgcn_mfma_f32_16x16x32_bf16(ak[mtj], bq[nti],
                                                                       f32x4{0.f, 0.f, 0.f, 0.f}, 0, 0, 0);
        // mask keys j >= 49  (j = 48 + 4g + r for mtj==3)
        #pragma unroll
        for (int nti = 0; nti < 4; ++nti)
            #pragma unroll
            for (int r = 0; r < 4; ++r)
                if (r != 0 || g != 0) sc[3][nti][r] = -1e30f;
        // softmax per query i = nti*16 + lr (unnormalized; 1/sum deferred)
        #pragma unroll
        for (int nti = 0; nti < 4; ++nti) {
            float m = sc[0][nti][0];
            #pragma unroll
            for (int mtj = 0; mtj < 4; ++mtj)
                #pragma unroll
                for (int r = 0; r < 4; ++r) m = fmaxf(m, sc[mtj][nti][r]);
            m = fmaxf(m, __shfl_xor(m, 16));
            m = fmaxf(m, __shfl_xor(m, 32));
            float sum = 0.f;
            #pragma unroll
            for (int mtj = 0; mtj < 4; ++mtj)
                #pragma unroll
                for (int r = 0; r < 4; ++r) {
                    float p = __expf(sc[mtj][nti][r] - m);
                    sc[mtj][nti][r] = p;
                    sum += p;
                }
            sum += __shfl_xor(sum, 16);
            sum += __shfl_xor(sum, 32);
            float rinv = 1.0f / sum;
            if (g == 0) *(float*)(lds + SRS + (h * 64 + nti * 16 + lr) * 4) = rinv;
        }
    }
    __syncthreads();   // all sQ/sK reads done -> safe to overwrite with sP

    // write P (bf16) into sP head region (aliases sQ/sK)
    {
        const int sPb = SQo + h * 8192;
        #pragma unroll
        for (int nti = 0; nti < 4; ++nti) {
            int i = nti * 16 + lr;
            #pragma unroll
            for (int mtj = 0; mtj < 4; ++mtj) {
                int j0b = (mtj * 16 + g * 4) * 2;   // byte offset of j0 within row
                unsigned w0 = f2b_u(sc[mtj][nti][0]) | (f2b_u(sc[mtj][nti][1]) << 16);
                unsigned w1 = f2b_u(sc[mtj][nti][2]) | (f2b_u(sc[mtj][nti][3]) << 16);
                *(unsigned*)(lds + sPb + i * 128 + SWZ(j0b, i))     = w0;
                *(unsigned*)(lds + sPb + i * 128 + SWZ(j0b + 4, i)) = w1;
            }
        }
    }
    __syncthreads();

    // ---------- phase 3: O = P @ V (MFMA), normalize, write sAo (aliases sX) ----------
    {
        const int sPb = SQo + h * 8192;
        bf16x8 ap[4][2], bv[2][2];
        #pragma unroll
        for (int mti = 0; mti < 4; ++mti)
            #pragma unroll
            for (int kk = 0; kk < 2; ++kk) {
                int i = mti * 16 + lr;
                ap[mti][kk] = *(bf16x8*)(lds + sPb + i * 128 + SWZ(g * 16 + kk * 64, i));
            }
        #pragma unroll
        for (int ntd = 0; ntd < 2; ++ntd)
            #pragma unroll
            for (int kk = 0; kk < 2; ++kk) {
                int d = hb + ntd * 16 + lr;
                bv[ntd][kk] = *(bf16x8*)(lds + SVt + d * 128 + SWZ(g * 16 + kk * 64, d));
            }
        f32x4 o[4][2];
        #pragma unroll
        for (int mti = 0; mti < 4; ++mti)
            #pragma unroll
            for (int ntd = 0; ntd < 2; ++ntd) o[mti][ntd] = f32x4{0.f, 0.f, 0.f, 0.f};
        #pragma unroll
        for (int kk = 0; kk < 2; ++kk)
            #pragma unroll
            for (int mti = 0; mti < 4; ++mti)
                #pragma unroll
                for (int ntd = 0; ntd < 2; ++ntd)
                    o[mti][ntd] = __builtin_amdgcn_mfma_f32_16x16x32_bf16(ap[mti][kk], bv[ntd][kk],
                                                                          o[mti][ntd], 0, 0, 0);
        #pragma unroll
        for (int mti = 0; mti < 4; ++mti)
            #pragma unroll
            for (int r = 0; r < 4; ++r) {
                int i = mti * 16 + g * 4 + r;
                if (i < 49) {
                    float rinv = *(float*)(lds + SRS + (h * 64 + i) * 4);
                    #pragma unroll
                    for (int ntd = 0; ntd < 2; ++ntd) {
                        int col = hb + ntd * 16 + lr;
                        float v = o[mti][ntd][r] * rinv;
                        *(short*)(lds + SX + i * 256 + SWZ(col * 2, i)) = (short)f2b_u(v);
                    }
                }
            }
    }
    __syncthreads();

    // ---------- phase 4: MO projection -> sMo (aliases sQ/sP region) ----------
    {
        bf16x8 a[4][4];
        #pragma unroll
        for (int mt = 0; mt < 4; ++mt)
            #pragma unroll
            for (int kk = 0; kk < 4; ++kk) {
                int row = mt * 16 + lr;
                a[mt][kk] = *(bf16x8*)(lds + SX + row * 256 + SWZ(g * 16 + kk * 64, row));
            }
        #pragma unroll
        for (int ntl = 0; ntl < 2; ++ntl) {
            const int oc = wv * 32 + ntl * 16 + lr;
            bf16x8 bfr[4];
            #pragma unroll
            for (int kk = 0; kk < 4; ++kk)
                bfr[kk] = load_wfrag<USEWS>(USEWS ? wsb + 49152 : nullptr, wmo, oc * 128 + g * 8 + kk * 32);
            f32x4 acc[4];
            #pragma unroll
            for (int mt = 0; mt < 4; ++mt) acc[mt] = f32x4{0.f, 0.f, 0.f, 0.f};
            #pragma unroll
            for (int kk = 0; kk < 4; ++kk)
                #pragma unroll
                for (int mt = 0; mt < 4; ++mt)
                    acc[mt] = __builtin_amdgcn_mfma_f32_16x16x32_bf16(a[mt][kk], bfr[kk], acc[mt], 0, 0, 0);
            const float bias = bmo[oc];
            #pragma unroll
            for (int mt = 0; mt < 4; ++mt)
                #pragma unroll
                for (int r = 0; r < 4; ++r) {
                    int row = mt * 16 + g * 4 + r;
                    *(short*)(lds + SQo + row * 256 + SWZ(oc * 2, row)) = (short)f2b_u(acc[mt][r] + bias);
                }
        }
    }
    __syncthreads();

    // ---------- phase 5: OUT projection + residual -> global ----------
    {
        bf16x8 a[4][4];
        #pragma unroll
        for (int mt = 0; mt < 4; ++mt)
            #pragma unroll
            for (int kk = 0; kk < 4; ++kk) {
                int row = mt * 16 + lr;
                a[mt][kk] = *(bf16x8*)(lds + SQo + row * 256 + SWZ(g * 16 + kk * 64, row));
            }
        #pragma unroll
        for (int ntl = 0; ntl < 2; ++ntl) {
            const int oc = wv * 32 + ntl * 16 + lr;
            bf16x8 bfr[4];
            #pragma unroll
            for (int kk = 0; kk < 4; ++kk)
                bfr[kk] = load_wfrag<USEWS>(USEWS ? wsb + 65536 : nullptr, wout, oc * 128 + g * 8 + kk * 32);
            f32x4 acc[4];
            #pragma unroll
            for (int mt = 0; mt < 4; ++mt) acc[mt] = f32x4{0.f, 0.f, 0.f, 0.f};
            #pragma unroll
            for (int kk = 0; kk < 4; ++kk)
                #pragma unroll
                for (int mt = 0; mt < 4; ++mt)
                    acc[mt] = __builtin_amdgcn_mfma_f32_16x16x32_bf16(a[mt][kk], bfr[kk], acc[mt], 0, 0, 0);
            const float bias = bout[oc];
            #pragma unroll
            for (int mt = 0; mt < 4; ++mt)
                #pragma unroll
                for (int r = 0; r < 4; ++r) {
                    int row = mt * 16 + g * 4 + r;
                    if (row < 49) {
                        size_t gi = base + (size_t)((row / 7) * 112 + (row % 7)) * 128 + oc;
                        out[gi] = x[gi] + acc[mt][r] + bias;
                    }
                }
        }
    }
}

} // namespace

extern "C" void kernel_launch(void* const* d_in, const int* in_sizes, int n_in,
                              void* d_out, int out_size, void* d_ws, size_t ws_size,
                              hipStream_t stream) {
    const float* x    = (const float*)d_in[0];
    const float* lng  = (const float*)d_in[1];
    const float* lnb  = (const float*)d_in[2];
    const float* wqkv = (const float*)d_in[3];
    const float* bqkv = (const float*)d_in[4];
    const float* wmo  = (const float*)d_in[5];
    const float* bmo  = (const float*)d_in[6];
    const float* wout = (const float*)d_in[7];
    const float* bout = (const float*)d_in[8];
    float* out = (float*)d_out;

    if (ws_size >= 81920 * sizeof(unsigned short)) {
        unsigned short* wsb = (unsigned short*)d_ws;
        conv_w<<<320, 256, 0, stream>>>(wqkv, wmo, wout, wsb);
        swin_mfma<true><<<4096, 256, 0, stream>>>(x, lng, lnb, wqkv, bqkv, wmo, bmo,
                                                  wout, bout, wsb, out);
    } else {
        swin_mfma<false><<<4096, 256, 0, stream>>>(x, lng, lnb, wqkv, bqkv, wmo, bmo,
                                                   wout, bout, nullptr, out);
    }
}

// Round 3
// 134.588 us; speedup vs baseline: 20.5954x; 1.3866x over previous
//
#include <hip/hip_runtime.h>
#include <hip/hip_bf16.h>

namespace {

typedef __attribute__((ext_vector_type(8))) short bf16x8;
typedef __attribute__((ext_vector_type(4))) float f32x4;

union BF8U { unsigned u[4]; bf16x8 v; };

__device__ __forceinline__ unsigned pk2(float a, float b) {
    union { __hip_bfloat162 h2; unsigned u; } c;
    c.h2 = __float22bfloat162_rn(float2{a, b});
    return c.u;
}
__device__ __forceinline__ unsigned short b1(float f) {
    union { __hip_bfloat16 h; unsigned short s; } c;
    c.h = __float2bfloat16(f);
    return c.s;
}
__device__ __forceinline__ int SWZ(int byteoff, int row) {
    return byteoff ^ ((row & 7) << 4);
}

// LDS: two 16 KB tiles, rows = 64 x 256B (128 bf16), XOR-swizzled.
constexpr int SX  = 0;        // LN out; after barrier#2 reused as MO-out
constexpr int SAO = 16384;    // attention out
constexpr int LDS_BYTES = 32768;

template<bool USEWS>
__device__ __forceinline__ bf16x8 load_wfrag(const unsigned short* wsb, const float* wf, int idx) {
    if constexpr (USEWS) {
        return *(const bf16x8*)(wsb + idx);
    } else {
        const float4 f0 = *(const float4*)(wf + idx);
        const float4 f1 = *(const float4*)(wf + idx + 4);
        bf16x8 r;
        r[0] = (short)b1(f0.x); r[1] = (short)b1(f0.y);
        r[2] = (short)b1(f0.z); r[3] = (short)b1(f0.w);
        r[4] = (short)b1(f1.x); r[5] = (short)b1(f1.y);
        r[6] = (short)b1(f1.z); r[7] = (short)b1(f1.w);
        return r;
    }
}

__global__ void conv_w(const float* __restrict__ wqkv, const float* __restrict__ wmo,
                       const float* __restrict__ wout, unsigned short* __restrict__ dst) {
    int i = blockIdx.x * 256 + threadIdx.x;
    float v;
    if (i < 49152)       v = wqkv[i];
    else if (i < 65536)  v = wmo[i - 49152];
    else if (i < 81920)  v = wout[i - 65536];
    else return;
    dst[i] = b1(v);
}

template<bool USEWS>
__global__ __launch_bounds__(256, 3)
void swin_mfma(const float* __restrict__ x,
               const float* __restrict__ lng, const float* __restrict__ lnb,
               const float* __restrict__ wqkv, const float* __restrict__ bqkv,
               const float* __restrict__ wmo,  const float* __restrict__ bmo,
               const float* __restrict__ wout, const float* __restrict__ bout,
               const unsigned short* __restrict__ wsb,
               float* __restrict__ out)
{
    __shared__ char lds[LDS_BYTES];

    const int wid  = blockIdx.x;
    const int b    = wid >> 8;
    const int wh   = (wid >> 4) & 15;
    const int ww   = wid & 15;
    const int t    = threadIdx.x;
    const int lane = t & 63;
    const int h    = t >> 6;          // wave == head
    const int lr   = lane & 15;
    const int g    = lane >> 4;       // 0..3
    const int hb   = h * 32;

    const size_t base = ((size_t)(b * 112 + wh * 7) * 112 + ww * 7) * 128;

    // ================= LayerNorm (4 lanes per token) =================
    if (t < 240) *(f32x4*)(lds + SX + 49 * 256 + t * 16) = f32x4{0.f, 0.f, 0.f, 0.f};
    {
        const int tok = t >> 2, q4 = t & 3;
        if (tok < 49) {
            const float* xr = x + base + (size_t)((tok / 7) * 112 + (tok % 7)) * 128;
            float4 xv[8];
            float s1 = 0.f, s2 = 0.f;
            #pragma unroll
            for (int j = 0; j < 8; ++j) {
                xv[j] = *(const float4*)(xr + j * 16 + q4 * 4);
                s1 += xv[j].x + xv[j].y + xv[j].z + xv[j].w;
                s2 += xv[j].x * xv[j].x + xv[j].y * xv[j].y
                    + xv[j].z * xv[j].z + xv[j].w * xv[j].w;
            }
            s1 += __shfl_xor(s1, 1); s1 += __shfl_xor(s1, 2);
            s2 += __shfl_xor(s2, 1); s2 += __shfl_xor(s2, 2);
            const float mu  = s1 * (1.f / 128.f);
            const float inv = rsqrtf(s2 * (1.f / 128.f) - mu * mu + 1e-5f);
            #pragma unroll
            for (int j = 0; j < 8; ++j) {
                const float4 gm = *(const float4*)(lng + j * 16 + q4 * 4);
                const float4 bt = *(const float4*)(lnb + j * 16 + q4 * 4);
                const float y0 = (xv[j].x - mu) * inv * gm.x + bt.x;
                const float y1 = (xv[j].y - mu) * inv * gm.y + bt.y;
                const float y2 = (xv[j].z - mu) * inv * gm.z + bt.z;
                const float y3 = (xv[j].w - mu) * inv * gm.w + bt.w;
                uint2 w; w.x = pk2(y0, y1); w.y = pk2(y2, y3);
                *(uint2*)(lds + SX + tok * 256 + SWZ(j * 32 + q4 * 8, tok)) = w;
            }
        }
    }
    __syncthreads();   // barrier #1

    // ============ phase 1A: Q,K projection, SWAPPED (D[o][token]) ============
    f32x4 aQ[2][4], aK[2][4];   // [o-tile][token-tile]
    #pragma unroll
    for (int ot = 0; ot < 2; ++ot)
        #pragma unroll
        for (int tt = 0; tt < 4; ++tt) {
            aQ[ot][tt] = f32x4{0.f, 0.f, 0.f, 0.f};
            aK[ot][tt] = f32x4{0.f, 0.f, 0.f, 0.f};
        }
    #pragma unroll
    for (int kk = 0; kk < 4; ++kk) {
        bf16x8 xa[4];
        #pragma unroll
        for (int tt = 0; tt < 4; ++tt) {
            int row = tt * 16 + lr;
            xa[tt] = *(bf16x8*)(lds + SX + row * 256 + SWZ(kk * 64 + g * 16, row));
        }
        #pragma unroll
        for (int ot = 0; ot < 2; ++ot) {
            bf16x8 wq = load_wfrag<USEWS>(wsb, wqkv, (hb + ot * 16 + lr) * 128 + kk * 32 + g * 8);
            bf16x8 wk = load_wfrag<USEWS>(wsb, wqkv, (128 + hb + ot * 16 + lr) * 128 + kk * 32 + g * 8);
            #pragma unroll
            for (int tt = 0; tt < 4; ++tt) {
                aQ[ot][tt] = __builtin_amdgcn_mfma_f32_16x16x32_bf16(wq, xa[tt], aQ[ot][tt], 0, 0, 0);
                aK[ot][tt] = __builtin_amdgcn_mfma_f32_16x16x32_bf16(wk, xa[tt], aK[ot][tt], 0, 0, 0);
            }
        }
    }
    unsigned pkQ[4][2][2], pkK[4][2][2];   // [token-tile][o-tile][pair]
    #pragma unroll
    for (int ot = 0; ot < 2; ++ot) {
        const float4 bq = *(const float4*)(bqkv + hb + ot * 16 + g * 4);
        const float4 bk = *(const float4*)(bqkv + 128 + hb + ot * 16 + g * 4);
        #pragma unroll
        for (int nti = 0; nti < 4; ++nti) {
            const float q0 = (aQ[ot][nti][0] + bq.x) * 0.17677669529663687f;
            const float q1 = (aQ[ot][nti][1] + bq.y) * 0.17677669529663687f;
            const float q2 = (aQ[ot][nti][2] + bq.z) * 0.17677669529663687f;
            const float q3 = (aQ[ot][nti][3] + bq.w) * 0.17677669529663687f;
            pkQ[nti][ot][0] = pk2(q0, q1); pkQ[nti][ot][1] = pk2(q2, q3);
            pkK[nti][ot][0] = pk2(aK[ot][nti][0] + bk.x, aK[ot][nti][1] + bk.y);
            pkK[nti][ot][1] = pk2(aK[ot][nti][2] + bk.z, aK[ot][nti][3] + bk.w);
        }
    }

    // ============ phase 1B: V projection, NORMAL (D[token][o]) ============
    f32x4 aV[4][2];   // [token-tile][o-tile]
    #pragma unroll
    for (int mt = 0; mt < 4; ++mt) {
        aV[mt][0] = f32x4{0.f, 0.f, 0.f, 0.f};
        aV[mt][1] = f32x4{0.f, 0.f, 0.f, 0.f};
    }
    #pragma unroll
    for (int kk = 0; kk < 4; ++kk) {
        bf16x8 xa[4];
        #pragma unroll
        for (int tt = 0; tt < 4; ++tt) {
            int row = tt * 16 + lr;
            xa[tt] = *(bf16x8*)(lds + SX + row * 256 + SWZ(kk * 64 + g * 16, row));
        }
        bf16x8 wv0 = load_wfrag<USEWS>(wsb, wqkv, (256 + hb + lr) * 128 + kk * 32 + g * 8);
        bf16x8 wv1 = load_wfrag<USEWS>(wsb, wqkv, (256 + hb + 16 + lr) * 128 + kk * 32 + g * 8);
        #pragma unroll
        for (int mt = 0; mt < 4; ++mt) {
            aV[mt][0] = __builtin_amdgcn_mfma_f32_16x16x32_bf16(xa[mt], wv0, aV[mt][0], 0, 0, 0);
            aV[mt][1] = __builtin_amdgcn_mfma_f32_16x16x32_bf16(xa[mt], wv1, aV[mt][1], 0, 0, 0);
        }
    }
    unsigned pkV[2][4][2];   // [d-tile][token-tile][pair]
    {
        const float bv0 = bqkv[256 + hb + lr];
        const float bv1 = bqkv[256 + hb + 16 + lr];
        #pragma unroll
        for (int mt = 0; mt < 4; ++mt) {
            pkV[0][mt][0] = pk2(aV[mt][0][0] + bv0, aV[mt][0][1] + bv0);
            pkV[0][mt][1] = pk2(aV[mt][0][2] + bv0, aV[mt][0][3] + bv0);
            pkV[1][mt][0] = pk2(aV[mt][1][0] + bv1, aV[mt][1][1] + bv1);
            pkV[1][mt][1] = pk2(aV[mt][1][2] + bv1, aV[mt][1][3] + bv1);
        }
    }

    // ---- in-wave redistribution: C-frag (idx on g*4+r, tiles) -> A/B-frag (idx on g*8+d) ----
    const int s01  = lr + ((lane & 16) ? 32 : 0);   // src lane for words 0,1
    const int s23  = s01 + 16;                      // src lane for words 2,3
    const bool hiT = (lane & 32) != 0;              // tile-parity select
    auto RD4 = [&](unsigned e0, unsigned e1, unsigned o0, unsigned o1) -> bf16x8 {
        BF8U r;
        const unsigned v0 = hiT ? o0 : e0;
        const unsigned v1 = hiT ? o1 : e1;
        r.u[0] = (unsigned)__shfl((int)v0, s01);
        r.u[1] = (unsigned)__shfl((int)v1, s01);
        r.u[2] = (unsigned)__shfl((int)v0, s23);
        r.u[3] = (unsigned)__shfl((int)v1, s23);
        return r.v;
    };

    // ============ phase 2: scores S[j][i] = mfma(K, Q), softmax ============
    f32x4 S[4][4];   // [j-tile][i-tile]
    {
        bf16x8 qb[4];
        #pragma unroll
        for (int nti = 0; nti < 4; ++nti)
            qb[nti] = RD4(pkQ[nti][0][0], pkQ[nti][0][1], pkQ[nti][1][0], pkQ[nti][1][1]);
        #pragma unroll
        for (int mtj = 0; mtj < 4; ++mtj) {
            bf16x8 ka = RD4(pkK[mtj][0][0], pkK[mtj][0][1], pkK[mtj][1][0], pkK[mtj][1][1]);
            #pragma unroll
            for (int nti = 0; nti < 4; ++nti)
                S[mtj][nti] = __builtin_amdgcn_mfma_f32_16x16x32_bf16(ka, qb[nti],
                                                                      f32x4{0.f, 0.f, 0.f, 0.f}, 0, 0, 0);
        }
    }
    // mask keys j >= 49 (j = 48 + g*4 + r in tile 3)
    #pragma unroll
    for (int nti = 0; nti < 4; ++nti)
        #pragma unroll
        for (int r = 0; r < 4; ++r)
            if (r != 0 || g != 0) S[3][nti][r] = -1e30f;

    unsigned pkP[4][4][2];   // [i-tile][j-tile][pair]
    #pragma unroll
    for (int nti = 0; nti < 4; ++nti) {
        float m = S[0][nti][0];
        #pragma unroll
        for (int mtj = 0; mtj < 4; ++mtj)
            #pragma unroll
            for (int r = 0; r < 4; ++r) m = fmaxf(m, S[mtj][nti][r]);
        m = fmaxf(m, __shfl_xor(m, 16));
        m = fmaxf(m, __shfl_xor(m, 32));
        float sum = 0.f;
        #pragma unroll
        for (int mtj = 0; mtj < 4; ++mtj)
            #pragma unroll
            for (int r = 0; r < 4; ++r) {
                const float p = __expf(S[mtj][nti][r] - m);
                S[mtj][nti][r] = p;
                sum += p;
            }
        sum += __shfl_xor(sum, 16);
        sum += __shfl_xor(sum, 32);
        const float rinv = 1.0f / sum;
        #pragma unroll
        for (int mtj = 0; mtj < 4; ++mtj) {
            pkP[nti][mtj][0] = pk2(S[mtj][nti][0] * rinv, S[mtj][nti][1] * rinv);
            pkP[nti][mtj][1] = pk2(S[mtj][nti][2] * rinv, S[mtj][nti][3] * rinv);
        }
    }

    // ============ phase 3: O = P @ V ============
    {
        bf16x8 vb[2][2];   // [kk][d-tile]
        #pragma unroll
        for (int kk = 0; kk < 2; ++kk)
            #pragma unroll
            for (int ntd = 0; ntd < 2; ++ntd)
                vb[kk][ntd] = RD4(pkV[ntd][2 * kk][0], pkV[ntd][2 * kk][1],
                                  pkV[ntd][2 * kk + 1][0], pkV[ntd][2 * kk + 1][1]);
        #pragma unroll
        for (int mti = 0; mti < 4; ++mti) {
            bf16x8 pa0 = RD4(pkP[mti][0][0], pkP[mti][0][1], pkP[mti][1][0], pkP[mti][1][1]);
            bf16x8 pa1 = RD4(pkP[mti][2][0], pkP[mti][2][1], pkP[mti][3][0], pkP[mti][3][1]);
            f32x4 O0 = f32x4{0.f, 0.f, 0.f, 0.f}, O1 = O0;
            O0 = __builtin_amdgcn_mfma_f32_16x16x32_bf16(pa0, vb[0][0], O0, 0, 0, 0);
            O0 = __builtin_amdgcn_mfma_f32_16x16x32_bf16(pa1, vb[1][0], O0, 0, 0, 0);
            O1 = __builtin_amdgcn_mfma_f32_16x16x32_bf16(pa0, vb[0][1], O1, 0, 0, 0);
            O1 = __builtin_amdgcn_mfma_f32_16x16x32_bf16(pa1, vb[1][1], O1, 0, 0, 0);
            #pragma unroll
            for (int r = 0; r < 4; ++r) {
                const int i = mti * 16 + g * 4 + r;
                *(unsigned short*)(lds + SAO + i * 256 + SWZ((hb + lr) * 2, i))      = b1(O0[r]);
                *(unsigned short*)(lds + SAO + i * 256 + SWZ((hb + 16 + lr) * 2, i)) = b1(O1[r]);
            }
        }
    }
    __syncthreads();   // barrier #2

    // ============ phase 4: MO projection -> sMo (reuses SX region) ============
    {
        bf16x8 a[4][4];
        #pragma unroll
        for (int mt = 0; mt < 4; ++mt)
            #pragma unroll
            for (int kk = 0; kk < 4; ++kk) {
                int row = mt * 16 + lr;
                a[mt][kk] = *(bf16x8*)(lds + SAO + row * 256 + SWZ(g * 16 + kk * 64, row));
            }
        #pragma unroll
        for (int ntl = 0; ntl < 2; ++ntl) {
            const int oc = h * 32 + ntl * 16 + lr;
            bf16x8 bfr[4];
            #pragma unroll
            for (int kk = 0; kk < 4; ++kk)
                bfr[kk] = load_wfrag<USEWS>(USEWS ? wsb + 49152 : nullptr, wmo, oc * 128 + kk * 32 + g * 8);
            f32x4 acc[4];
            #pragma unroll
            for (int mt = 0; mt < 4; ++mt) acc[mt] = f32x4{0.f, 0.f, 0.f, 0.f};
            #pragma unroll
            for (int kk = 0; kk < 4; ++kk)
                #pragma unroll
                for (int mt = 0; mt < 4; ++mt)
                    acc[mt] = __builtin_amdgcn_mfma_f32_16x16x32_bf16(a[mt][kk], bfr[kk], acc[mt], 0, 0, 0);
            const float bias = bmo[oc];
            #pragma unroll
            for (int mt = 0; mt < 4; ++mt)
                #pragma unroll
                for (int r = 0; r < 4; ++r) {
                    int row = mt * 16 + g * 4 + r;
                    *(unsigned short*)(lds + SX + row * 256 + SWZ(oc * 2, row)) = b1(acc[mt][r] + bias);
                }
        }
    }
    __syncthreads();   // barrier #3

    // ============ phase 5: OUT projection + residual -> global ============
    {
        bf16x8 a[4][4];
        #pragma unroll
        for (int mt = 0; mt < 4; ++mt)
            #pragma unroll
            for (int kk = 0; kk < 4; ++kk) {
                int row = mt * 16 + lr;
                a[mt][kk] = *(bf16x8*)(lds + SX + row * 256 + SWZ(g * 16 + kk * 64, row));
            }
        #pragma unroll
        for (int ntl = 0; ntl < 2; ++ntl) {
            const int oc = h * 32 + ntl * 16 + lr;
            bf16x8 bfr[4];
            #pragma unroll
            for (int kk = 0; kk < 4; ++kk)
                bfr[kk] = load_wfrag<USEWS>(USEWS ? wsb + 65536 : nullptr, wout, oc * 128 + kk * 32 + g * 8);
            f32x4 acc[4];
            #pragma unroll
            for (int mt = 0; mt < 4; ++mt) acc[mt] = f32x4{0.f, 0.f, 0.f, 0.f};
            #pragma unroll
            for (int kk = 0; kk < 4; ++kk)
                #pragma unroll
                for (int mt = 0; mt < 4; ++mt)
                    acc[mt] = __builtin_amdgcn_mfma_f32_16x16x32_bf16(a[mt][kk], bfr[kk], acc[mt], 0, 0, 0);
            const float bias = bout[oc];
            #pragma unroll
            for (int mt = 0; mt < 4; ++mt)
                #pragma unroll
                for (int r = 0; r < 4; ++r) {
                    const int row = mt * 16 + g * 4 + r;
                    if (row < 49) {
                        const size_t gi = base + (size_t)((row / 7) * 112 + (row % 7)) * 128 + oc;
                        out[gi] = x[gi] + acc[mt][r] + bias;
                    }
                }
        }
    }
}

} // namespace

extern "C" void kernel_launch(void* const* d_in, const int* in_sizes, int n_in,
                              void* d_out, int out_size, void* d_ws, size_t ws_size,
                              hipStream_t stream) {
    const float* x    = (const float*)d_in[0];
    const float* lng  = (const float*)d_in[1];
    const float* lnb  = (const float*)d_in[2];
    const float* wqkv = (const float*)d_in[3];
    const float* bqkv = (const float*)d_in[4];
    const float* wmo  = (const float*)d_in[5];
    const float* bmo  = (const float*)d_in[6];
    const float* wout = (const float*)d_in[7];
    const float* bout = (const float*)d_in[8];
    float* out = (float*)d_out;

    if (ws_size >= 81920 * sizeof(unsigned short)) {
        unsigned short* wsb = (unsigned short*)d_ws;
        conv_w<<<320, 256, 0, stream>>>(wqkv, wmo, wout, wsb);
        swin_mfma<true><<<4096, 256, 0, stream>>>(x, lng, lnb, wqkv, bqkv, wmo, bmo,
                                                  wout, bout, wsb, out);
    } else {
        swin_mfma<false><<<4096, 256, 0, stream>>>(x, lng, lnb, wqkv, bqkv, wmo, bmo,
                                                   wout, bout, nullptr, out);
    }
}